// Round 1
// baseline (771.002 us; speedup 1.0000x reference)
//
#include <hip/hip_runtime.h>
#include <hip/hip_bf16.h>

#define NTOT 2048
#define DD 256
#define BSZ 4

// ---------------- block reduce (256 threads) ----------------
__device__ __forceinline__ float blockReduceSum256(float v) {
    __shared__ float red[4];
    for (int off = 32; off > 0; off >>= 1) v += __shfl_down(v, off);
    int lane = threadIdx.x & 63, w = threadIdx.x >> 6;
    __syncthreads();                 // protect red[] reuse across successive calls
    if (lane == 0) red[w] = v;
    __syncthreads();
    return red[0] + red[1] + red[2] + red[3];
}

// ---------------- pos stats: mean/scale for 3 cols ----------------
__global__ void pos_stats_kernel(const float* __restrict__ pos, float* __restrict__ stats) {
    int tid = threadIdx.x;
    float s[3] = {0.f, 0.f, 0.f};
    for (int i = tid; i < NTOT; i += 256)
        for (int c = 0; c < 3; ++c) s[c] += pos[i * 3 + c];
    float m[3];
    for (int c = 0; c < 3; ++c) m[c] = blockReduceSum256(s[c]) / (float)NTOT;
    float q[3] = {0.f, 0.f, 0.f};
    for (int i = tid; i < NTOT; i += 256)
        for (int c = 0; c < 3; ++c) { float d = pos[i * 3 + c] - m[c]; q[c] += d * d; }
    for (int c = 0; c < 3; ++c) {
        float t = blockReduceSum256(q[c]);
        if (tid == 0) {
            // tiled B times; std over B*N samples with ddof=1
            float var = ((float)BSZ * t) / ((float)BSZ * NTOT - 1.0f);
            stats[c] = m[c];
            stats[3 + c] = 1.0f / (sqrtf(var) + 1e-8f);
        }
    }
}

// q[i,d] = silu(pn[i,:] @ pw1[:,d] + pb1[d])
__global__ void pe_q_kernel(const float* __restrict__ pos, const float* __restrict__ stats,
                            const float* __restrict__ pw1, const float* __restrict__ pb1,
                            float* __restrict__ q) {
    int i = blockIdx.x, d = threadIdx.x;
    float acc = pb1[d];
    for (int c = 0; c < 3; ++c) {
        float pn = (pos[i * 3 + c] - stats[c]) * stats[3 + c];
        acc += pn * pw1[c * DD + d];
    }
    q[i * DD + d] = acc / (1.0f + expf(-acc));
}

// h[row,d] = x[row,:16] @ in_w[:,d] + in_b[d] + pe[row % N, d]
__global__ void init_h_kernel(const float* __restrict__ x, const float* __restrict__ in_w,
                              const float* __restrict__ in_b, const float* __restrict__ pe,
                              float* __restrict__ h) {
    int row = blockIdx.x, d = threadIdx.x;
    float acc = in_b[d];
    for (int k = 0; k < 16; ++k) acc += x[row * 16 + k] * in_w[k * DD + d];
    h[row * DD + d] = acc + pe[(row & (NTOT - 1)) * DD + d];
}

// ---------------- CSR build (deterministic) ----------------
__global__ void csr_count_kernel(const float* __restrict__ adj, int* __restrict__ counts) {
    int i = blockIdx.x, tid = threadIdx.x;
    float c = 0.f;
    for (int j = tid; j < NTOT; j += 256) c += (adj[i * NTOT + j] != 0.f) ? 1.f : 0.f;
    float t = blockReduceSum256(c);
    if (tid == 0) counts[i] = (int)(t + 0.5f);
}

__global__ void scan_kernel(const int* __restrict__ counts, int* __restrict__ row_ptr) {
    __shared__ int csum[256];
    int tid = threadIdx.x;
    int local[8]; int tot = 0;
    for (int u = 0; u < 8; ++u) { local[u] = counts[tid * 8 + u]; tot += local[u]; }
    csum[tid] = tot; __syncthreads();
    for (int off = 1; off < 256; off <<= 1) {
        int v = (tid >= off) ? csum[tid - off] : 0;
        __syncthreads();
        csum[tid] += v;
        __syncthreads();
    }
    int run = csum[tid] - tot;  // exclusive prefix
    for (int u = 0; u < 8; ++u) { row_ptr[tid * 8 + u] = run; run += local[u]; }
    if (tid == 255) row_ptr[NTOT] = run;
}

__global__ void csr_fill_kernel(const float* __restrict__ adj, const int* __restrict__ row_ptr,
                                int* __restrict__ col) {
    int i = blockIdx.x, lane = threadIdx.x;  // 64 threads
    int base = row_ptr[i];
    int run = 0;
    for (int j0 = 0; j0 < NTOT; j0 += 64) {
        int j = j0 + lane;
        bool pred = adj[i * NTOT + j] != 0.f;
        unsigned long long mask = __ballot(pred);
        if (pred) {
            int pos = run + __popcll(mask & ((1ull << lane) - 1ull));
            col[base + pos] = j;
        }
        run += __popcll(mask);
    }
}

// ---------------- maps ----------------
__global__ void init_maps_kernel(int* __restrict__ orig, int* __restrict__ inv) {
    int t = blockIdx.x * 256 + threadIdx.x;  // B*N
    int i = t & (NTOT - 1);
    orig[t] = i; inv[t] = i;
}
__global__ void inv_reset_kernel(int* __restrict__ inv) {
    int t = blockIdx.x * 256 + threadIdx.x;
    inv[t] = -1;
}
__global__ void inv_set_kernel(const int* __restrict__ orig, int* __restrict__ inv, int k) {
    int t = blockIdx.x * 256 + threadIdx.x;  // B*k (exact multiple of 256)
    int b = t / k, r = t - b * k;
    inv[b * NTOT + orig[b * NTOT + r]] = r;
}

// ---------------- LayerNorm ----------------
__global__ void ln_kernel(const float* __restrict__ h, float* __restrict__ hn,
                          const float* __restrict__ g, const float* __restrict__ b) {
    int r = blockIdx.x, d = threadIdx.x;
    float x = h[r * DD + d];
    float m = blockReduceSum256(x) / (float)DD;
    float diff = x - m;
    float v = blockReduceSum256(diff * diff) / (float)DD;
    hn[r * DD + d] = diff * rsqrtf(v + 1e-5f) * g[d] + b[d];
}

// t = (1+eps)*hn + sum_{neighbors} hn   (sparse via original-adj CSR)
__global__ void agg_kernel(const float* __restrict__ hn, float* __restrict__ t,
                           const int* __restrict__ row_ptr, const int* __restrict__ col,
                           const int* __restrict__ orig, const int* __restrict__ inv,
                           const float* __restrict__ beps, int blk, int n) {
    int r = blockIdx.x;            // 0..B*n-1
    int b = r / n, i = r - b * n;
    int d = threadIdx.x;
    float acc = (1.0f + beps[blk]) * hn[r * DD + d];
    int o = orig[b * NTOT + i];
    int s = row_ptr[o], e = row_ptr[o + 1];
    const int* invb = inv + b * NTOT;
    const float* hnb = hn + (size_t)b * n * DD;
    for (int p = s; p < e; ++p) {
        int j = invb[col[p]];
        if (j >= 0) acc += hnb[j * DD + d];
    }
    t[r * DD + d] = acc;
}

// ---------------- f32 tiled matmul: C[rows,256] = act(A @ W + bias) (+= opt) ----------------
#define BM 64
#define BN 64
#define BKT 16
template <int ACT_SILU, int ACCUM>
__global__ void mm256(const float* __restrict__ A, const float* __restrict__ W,
                      const float* __restrict__ bias, float* __restrict__ C, int rows) {
    __shared__ float As[BKT][BM + 1];
    __shared__ float Ws[BKT][BN + 1];
    int tid = threadIdx.x;
    int tx = tid & 15, ty = tid >> 4;
    int rowBase = blockIdx.x * BM;
    int colBase = blockIdx.y * BN;
    float acc[4][4] = {};
    for (int k0 = 0; k0 < DD; k0 += BKT) {
        for (int u = 0; u < 4; ++u) {
            int e = tid * 4 + u;
            int r = e >> 4, kk = e & 15;
            As[kk][r] = A[(size_t)(rowBase + r) * DD + k0 + kk];
        }
        for (int u = 0; u < 4; ++u) {
            int e = tid * 4 + u;
            int kk = e >> 6, c = e & 63;
            Ws[kk][c] = W[(size_t)(k0 + kk) * DD + colBase + c];
        }
        __syncthreads();
        for (int kk = 0; kk < BKT; ++kk) {
            float ar[4], br[4];
            for (int i = 0; i < 4; ++i) ar[i] = As[kk][ty * 4 + i];
            for (int j = 0; j < 4; ++j) br[j] = Ws[kk][tx * 4 + j];
            for (int i = 0; i < 4; ++i)
                for (int j = 0; j < 4; ++j) acc[i][j] += ar[i] * br[j];
        }
        __syncthreads();
    }
    for (int i = 0; i < 4; ++i) {
        int r = rowBase + ty * 4 + i;
        for (int j = 0; j < 4; ++j) {
            int c = colBase + tx * 4 + j;
            float v = acc[i][j] + bias[c];
            if (ACT_SILU) v = v / (1.0f + expf(-v));
            if (ACCUM) C[(size_t)r * DD + c] += v;
            else       C[(size_t)r * DD + c] = v;
        }
    }
}

// ---------------- pooling ----------------
__global__ void score_kernel(const float* __restrict__ h, const float* __restrict__ p,
                             float* __restrict__ scores, int n) {
    int r = blockIdx.x;
    int b = r / n, i = r - b * n;
    int d = threadIdx.x;
    float hv = h[r * DD + d], pv = p[d];
    float hp = blockReduceSum256(hv * pv);
    float pp = blockReduceSum256(pv * pv);
    if (d == 0) scores[b * NTOT + i] = hp / sqrtf(pp);
}

__global__ void topk_kernel(const float* __restrict__ scores, const int* __restrict__ orig_cur,
                            int* __restrict__ orig_next, int* __restrict__ idx_local,
                            float* __restrict__ gate, int n, int k) {
    __shared__ float sv[2048];
    __shared__ int sg[256], se[256];
    int b = blockIdx.x;
    const float* sc = scores + b * NTOT;
    int tid = threadIdx.x;
    for (int i = tid; i < n; i += 256) sv[i] = sc[i];
    __syncthreads();
    // bitonic sort ascending
    for (int sz = 2; sz <= n; sz <<= 1) {
        for (int j = sz >> 1; j > 0; j >>= 1) {
            for (int i = tid; i < n; i += 256) {
                int l = i ^ j;
                if (l > i) {
                    float a = sv[i], c = sv[l];
                    bool up = ((i & sz) == 0);
                    bool sw = up ? (a > c) : (a < c);
                    if (sw) { sv[i] = c; sv[l] = a; }
                }
            }
            __syncthreads();
        }
    }
    float thr = sv[n - k];  // k-th largest
    // per-chunk counts of (>thr) and (==thr)
    int chunk = n / 256;
    int base = tid * chunk;
    int cgt = 0, ceq = 0;
    for (int u = 0; u < chunk; ++u) {
        float s = sc[base + u];
        cgt += (s > thr); ceq += (s == thr);
    }
    sg[tid] = cgt; se[tid] = ceq; __syncthreads();
    for (int off = 1; off < 256; off <<= 1) {
        int vg = (tid >= off) ? sg[tid - off] : 0;
        int ve = (tid >= off) ? se[tid - off] : 0;
        __syncthreads();
        sg[tid] += vg; se[tid] += ve;
        __syncthreads();
    }
    int total_gt = sg[255];
    int ties = k - total_gt;             // how many ==thr to take (lowest indices first)
    int gtb = sg[tid] - cgt, eqb = se[tid] - ceq;  // exclusive prefixes
    for (int u = 0; u < chunk; ++u) {
        int i = base + u;
        float s = sc[i];
        bool isgt = (s > thr), iseq = (s == thr);
        bool keep = isgt || (iseq && eqb < ties);
        if (keep) {
            int pos = gtb + (eqb < ties ? eqb : ties);  // kept-before-i
            idx_local[b * NTOT + pos] = i;
            gate[b * NTOT + pos] = tanhf(s);
            orig_next[b * NTOT + pos] = orig_cur[b * NTOT + i];
        }
        gtb += isgt; eqb += iseq;
    }
}

__global__ void gather_kernel(const float* __restrict__ h, const int* __restrict__ idx_local,
                              const float* __restrict__ gate, float* __restrict__ hout,
                              int n_old, int k) {
    int r = blockIdx.x;  // B*k
    int b = r / k, rr = r - b * k;
    int d = threadIdx.x;
    int src = idx_local[b * NTOT + rr];
    hout[(size_t)r * DD + d] = h[(size_t)(b * n_old + src) * DD + d] * gate[b * NTOT + rr];
}

// ---------------- readout ----------------
__global__ void readout_kernel(const float* __restrict__ h, float* __restrict__ feat) {
    int bd = blockIdx.x;  // B*256
    int b = bd >> 8, d = bd & 255;
    int i = threadIdx.x;  // node (n=256)
    float x = h[(size_t)(b * 256 + i) * DD + d];
    float m = blockReduceSum256(x) / 256.0f;
    float diff = x - m;
    float s2 = blockReduceSum256(diff * diff);
    if (i == 0) {
        feat[b * 512 + d] = m;
        feat[b * 512 + 256 + d] = sqrtf(s2 / 255.0f) + 1e-6f;  // ddof=1
    }
}

__global__ void final_kernel(const float* __restrict__ feat, const float* __restrict__ lw,
                             const float* __restrict__ lb, float* __restrict__ out) {
    int b = blockIdx.x, l = threadIdx.x;  // 128 threads
    float acc = lb[l];
    const float* f = feat + b * 512;
    for (int k = 0; k < 512; ++k) acc += f[k] * lw[k * 128 + l];
    out[b * 128 + l] = acc;
}

extern "C" void kernel_launch(void* const* d_in, const int* in_sizes, int n_in,
                              void* d_out, int out_size, void* d_ws, size_t ws_size,
                              hipStream_t stream) {
    (void)in_sizes; (void)n_in; (void)out_size; (void)ws_size;
    const float* x     = (const float*)d_in[0];
    const float* adj   = (const float*)d_in[1];
    const float* pos   = (const float*)d_in[2];
    const float* in_w  = (const float*)d_in[3];
    const float* in_b  = (const float*)d_in[4];
    const float* pw1   = (const float*)d_in[5];
    const float* pb1   = (const float*)d_in[6];
    const float* pw2   = (const float*)d_in[7];
    const float* pb2   = (const float*)d_in[8];
    const float* bg    = (const float*)d_in[9];
    const float* bb    = (const float*)d_in[10];
    const float* bw1   = (const float*)d_in[11];
    const float* bb1   = (const float*)d_in[12];
    const float* bw2   = (const float*)d_in[13];
    const float* bb2   = (const float*)d_in[14];
    const float* beps  = (const float*)d_in[15];
    const float* poolp = (const float*)d_in[16];
    const float* lw    = (const float*)d_in[17];
    const float* lb    = (const float*)d_in[18];
    float* out = (float*)d_out;

    char* wp = (char*)d_ws;
    auto alloc = [&](size_t bytes) -> void* {
        void* p = (void*)wp;
        wp += (bytes + 255) & ~(size_t)255;
        return p;
    };
    const size_t HBYTES = (size_t)BSZ * NTOT * DD * sizeof(float);  // 8.39 MB
    float* h    = (float*)alloc(HBYTES);
    float* bufB = (float*)alloc(HBYTES);
    float* bufC = (float*)alloc(HBYTES);
    float* stats   = (float*)alloc(8 * sizeof(float));
    float* scores  = (float*)alloc(BSZ * NTOT * sizeof(float));
    float* gate    = (float*)alloc(BSZ * NTOT * sizeof(float));
    int*   origA   = (int*)alloc(BSZ * NTOT * sizeof(int));
    int*   origB   = (int*)alloc(BSZ * NTOT * sizeof(int));
    int*   idxl    = (int*)alloc(BSZ * NTOT * sizeof(int));
    int*   inv     = (int*)alloc(BSZ * NTOT * sizeof(int));
    int*   counts  = (int*)alloc(NTOT * sizeof(int));
    int*   row_ptr = (int*)alloc((NTOT + 1) * sizeof(int));
    int*   col     = (int*)alloc((size_t)NTOT * 64 * sizeof(int));  // cap 64 nbrs/row (mean ~8)
    float* feat    = (float*)alloc(BSZ * 512 * sizeof(float));

    // ---- positional embedding: pe (stored in bufC), q in bufB ----
    pos_stats_kernel<<<1, 256, 0, stream>>>(pos, stats);
    pe_q_kernel<<<NTOT, 256, 0, stream>>>(pos, stats, pw1, pb1, bufB);
    mm256<0, 0><<<dim3(NTOT / BM, DD / BN), 256, 0, stream>>>(bufB, pw2, pb2, bufC, NTOT);
    // ---- h init ----
    init_h_kernel<<<BSZ * NTOT, 256, 0, stream>>>(x, in_w, in_b, bufC, h);
    // ---- CSR of original adjacency ----
    csr_count_kernel<<<NTOT, 256, 0, stream>>>(adj, counts);
    scan_kernel<<<1, 256, 0, stream>>>(counts, row_ptr);
    csr_fill_kernel<<<NTOT, 64, 0, stream>>>(adj, row_ptr, col);
    // ---- index maps ----
    init_maps_kernel<<<(BSZ * NTOT) / 256, 256, 0, stream>>>(origA, inv);

    float* hcur = h;
    int* orig = origA;
    int* orign = origB;
    int n = NTOT;
    int blk = 0;
    for (int dep = 0; dep < 4; ++dep) {
        for (int s = 0; s < 2; ++s) {
            int rows = BSZ * n;
            ln_kernel<<<rows, 256, 0, stream>>>(hcur, bufB, bg + blk * DD, bb + blk * DD);
            agg_kernel<<<rows, 256, 0, stream>>>(bufB, bufC, row_ptr, col, orig, inv, beps, blk, n);
            mm256<1, 0><<<dim3(rows / BM, DD / BN), 256, 0, stream>>>(
                bufC, bw1 + (size_t)blk * DD * DD, bb1 + blk * DD, bufB, rows);
            mm256<0, 1><<<dim3(rows / BM, DD / BN), 256, 0, stream>>>(
                bufB, bw2 + (size_t)blk * DD * DD, bb2 + blk * DD, hcur, rows);
            ++blk;
        }
        if (dep < 3) {
            int k = n / 2;
            score_kernel<<<BSZ * n, 256, 0, stream>>>(hcur, poolp + dep * DD, scores, n);
            topk_kernel<<<BSZ, 256, 0, stream>>>(scores, orig, orign, idxl, gate, n, k);
            gather_kernel<<<BSZ * k, 256, 0, stream>>>(hcur, idxl, gate, bufC, n, k);
            { float* t = hcur; hcur = bufC; bufC = t; }
            { int* t = orig; orig = orign; orign = t; }
            inv_reset_kernel<<<(BSZ * NTOT) / 256, 256, 0, stream>>>(inv);
            inv_set_kernel<<<(BSZ * k) / 256, 256, 0, stream>>>(orig, inv, k);
            n = k;
        }
    }
    // ---- readout ----
    readout_kernel<<<BSZ * 256, 256, 0, stream>>>(hcur, feat);
    final_kernel<<<BSZ, 128, 0, stream>>>(feat, lw, lb, out);
}

// Round 2
// 365.142 us; speedup vs baseline: 2.1115x; 2.1115x over previous
//
#include <hip/hip_runtime.h>
#include <hip/hip_bf16.h>

#define NTOT 2048
#define DD 256
#define BSZ 4

typedef __bf16 bf16_t;
typedef __attribute__((ext_vector_type(8))) __bf16 bf16x8;
typedef __attribute__((ext_vector_type(4))) float f32x4;

// ---------------- block reduce (256 threads) ----------------
__device__ __forceinline__ float blockReduceSum256(float v) {
    __shared__ float red[4];
    for (int off = 32; off > 0; off >>= 1) v += __shfl_down(v, off);
    int lane = threadIdx.x & 63, w = threadIdx.x >> 6;
    __syncthreads();                 // protect red[] reuse across successive calls
    if (lane == 0) red[w] = v;
    __syncthreads();
    return red[0] + red[1] + red[2] + red[3];
}

// ---------------- pos stats: mean/scale for 3 cols ----------------
__global__ void pos_stats_kernel(const float* __restrict__ pos, float* __restrict__ stats) {
    int tid = threadIdx.x;
    float s[3] = {0.f, 0.f, 0.f};
    for (int i = tid; i < NTOT; i += 256)
        for (int c = 0; c < 3; ++c) s[c] += pos[i * 3 + c];
    float m[3];
    for (int c = 0; c < 3; ++c) m[c] = blockReduceSum256(s[c]) / (float)NTOT;
    float q[3] = {0.f, 0.f, 0.f};
    for (int i = tid; i < NTOT; i += 256)
        for (int c = 0; c < 3; ++c) { float d = pos[i * 3 + c] - m[c]; q[c] += d * d; }
    for (int c = 0; c < 3; ++c) {
        float t = blockReduceSum256(q[c]);
        if (tid == 0) {
            float var = ((float)BSZ * t) / ((float)BSZ * NTOT - 1.0f);
            stats[c] = m[c];
            stats[3 + c] = 1.0f / (sqrtf(var) + 1e-8f);
        }
    }
}

// q[i,d] = silu(pn[i,:] @ pw1[:,d] + pb1[d])  -> bf16
__global__ void pe_q_kernel(const float* __restrict__ pos, const float* __restrict__ stats,
                            const float* __restrict__ pw1, const float* __restrict__ pb1,
                            bf16_t* __restrict__ q) {
    int i = blockIdx.x, d = threadIdx.x;
    float acc = pb1[d];
    for (int c = 0; c < 3; ++c) {
        float pn = (pos[i * 3 + c] - stats[c]) * stats[3 + c];
        acc += pn * pw1[c * DD + d];
    }
    acc = acc / (1.0f + expf(-acc));
    q[i * DD + d] = (bf16_t)acc;
}

// h[row,d] = x[row,:16] @ in_w[:,d] + in_b[d] + pe[row % N, d]
__global__ void init_h_kernel(const float* __restrict__ x, const float* __restrict__ in_w,
                              const float* __restrict__ in_b, const float* __restrict__ pe,
                              float* __restrict__ h) {
    int row = blockIdx.x, d = threadIdx.x;
    float acc = in_b[d];
    for (int k = 0; k < 16; ++k) acc += x[row * 16 + k] * in_w[k * DD + d];
    h[row * DD + d] = acc + pe[(row & (NTOT - 1)) * DD + d];
}

// ---------------- weight prep: Wt[m][n][k] = bf16(W_m[k][n]) ----------------
// m 0..7 = bw1, 8..15 = bw2, 16 = pw2
__global__ void wprep_kernel(const float* __restrict__ bw1, const float* __restrict__ bw2,
                             const float* __restrict__ pw2, bf16_t* __restrict__ Wt) {
    int m = blockIdx.x, nb = blockIdx.y * 16, kb = blockIdx.z * 16;
    const float* W = (m < 8) ? (bw1 + (size_t)m * DD * DD)
                  : (m < 16) ? (bw2 + (size_t)(m - 8) * DD * DD)
                             : pw2;
    __shared__ float s[16][17];
    int i = threadIdx.x >> 4, j = threadIdx.x & 15;
    s[i][j] = W[(size_t)(kb + i) * DD + nb + j];
    __syncthreads();
    Wt[(size_t)m * DD * DD + (size_t)(nb + i) * DD + kb + j] = (bf16_t)s[j][i];
}

// ---------------- CSR build (deterministic) ----------------
__global__ void csr_count_kernel(const float* __restrict__ adj, int* __restrict__ counts) {
    int i = blockIdx.x, tid = threadIdx.x;
    float c = 0.f;
    for (int j = tid; j < NTOT; j += 256) c += (adj[i * NTOT + j] != 0.f) ? 1.f : 0.f;
    float t = blockReduceSum256(c);
    if (tid == 0) counts[i] = (int)(t + 0.5f);
}

__global__ void scan_kernel(const int* __restrict__ counts, int* __restrict__ row_ptr) {
    __shared__ int csum[256];
    int tid = threadIdx.x;
    int local[8]; int tot = 0;
    for (int u = 0; u < 8; ++u) { local[u] = counts[tid * 8 + u]; tot += local[u]; }
    csum[tid] = tot; __syncthreads();
    for (int off = 1; off < 256; off <<= 1) {
        int v = (tid >= off) ? csum[tid - off] : 0;
        __syncthreads();
        csum[tid] += v;
        __syncthreads();
    }
    int run = csum[tid] - tot;  // exclusive prefix
    for (int u = 0; u < 8; ++u) { row_ptr[tid * 8 + u] = run; run += local[u]; }
    if (tid == 255) row_ptr[NTOT] = run;
}

__global__ void csr_fill_kernel(const float* __restrict__ adj, const int* __restrict__ row_ptr,
                                int* __restrict__ col) {
    int i = blockIdx.x, lane = threadIdx.x;  // 64 threads
    int base = row_ptr[i];
    int run = 0;
    for (int j0 = 0; j0 < NTOT; j0 += 64) {
        int j = j0 + lane;
        bool pred = adj[i * NTOT + j] != 0.f;
        unsigned long long mask = __ballot(pred);
        if (pred) {
            int pos = run + __popcll(mask & ((1ull << lane) - 1ull));
            col[base + pos] = j;
        }
        run += __popcll(mask);
    }
}

// ---------------- maps ----------------
__global__ void init_maps_kernel(int* __restrict__ orig, int* __restrict__ inv) {
    int t = blockIdx.x * 256 + threadIdx.x;  // B*N
    int i = t & (NTOT - 1);
    orig[t] = i; inv[t] = i;
}
__global__ void inv_reset_kernel(int* __restrict__ inv) {
    int t = blockIdx.x * 256 + threadIdx.x;
    inv[t] = -1;
}
__global__ void inv_set_kernel(const int* __restrict__ orig, int* __restrict__ inv, int k) {
    int t = blockIdx.x * 256 + threadIdx.x;  // B*k (exact multiple of 256)
    int b = t / k, r = t - b * k;
    inv[b * NTOT + orig[b * NTOT + r]] = r;
}

// ---------------- LayerNorm ----------------
__global__ void ln_kernel(const float* __restrict__ h, float* __restrict__ hn,
                          const float* __restrict__ g, const float* __restrict__ b) {
    int r = blockIdx.x, d = threadIdx.x;
    float x = h[r * DD + d];
    float m = blockReduceSum256(x) / (float)DD;
    float diff = x - m;
    float v = blockReduceSum256(diff * diff) / (float)DD;
    hn[r * DD + d] = diff * rsqrtf(v + 1e-5f) * g[d] + b[d];
}

// t = (1+eps)*hn + sum_{neighbors} hn   (sparse via original-adj CSR) -> bf16
__global__ void agg_kernel(const float* __restrict__ hn, bf16_t* __restrict__ t,
                           const int* __restrict__ row_ptr, const int* __restrict__ col,
                           const int* __restrict__ orig, const int* __restrict__ inv,
                           const float* __restrict__ beps, int blk, int n) {
    int r = blockIdx.x;            // 0..B*n-1
    int b = r / n, i = r - b * n;
    int d = threadIdx.x;
    float acc = (1.0f + beps[blk]) * hn[r * DD + d];
    int o = orig[b * NTOT + i];
    int s = row_ptr[o], e = row_ptr[o + 1];
    const int* invb = inv + b * NTOT;
    const float* hnb = hn + (size_t)b * n * DD;
    for (int p = s; p < e; ++p) {
        int j = invb[col[p]];
        if (j >= 0) acc += hnb[j * DD + d];
    }
    t[r * DD + d] = (bf16_t)acc;
}

// ---------------- bf16 MFMA matmul: C[rows,256] = act(A @ Wt^T + bias) ----------------
// A bf16 [rows][256]; Wt bf16 [256][256] with Wt[n][k] = W[k][n].
// One wave per block; 32x32 output tile; grid (rows/32, 8).
// MODE 0: plain f32 store; MODE 1: silu -> bf16 store; MODE 2: f32 accumulate (+=)
template <int MODE>
__global__ void __launch_bounds__(64) mm_bf16(const bf16_t* __restrict__ A,
                                              const bf16_t* __restrict__ Wt,
                                              const float* __restrict__ bias,
                                              void* __restrict__ Cout, int rows) {
    int l = threadIdx.x;
    int r0 = blockIdx.x * 32 + (l & 15);
    int c0 = blockIdx.y * 32 + (l & 15);
    int kb = (l >> 4) * 8;
    f32x4 acc[2][2] = {};
    const bf16_t* a0p = A + (size_t)r0 * DD + kb;
    const bf16_t* a1p = a0p + 16 * DD;
    const bf16_t* b0p = Wt + (size_t)c0 * DD + kb;
    const bf16_t* b1p = b0p + 16 * DD;
#pragma unroll
    for (int k0 = 0; k0 < DD; k0 += 32) {
        bf16x8 a0 = *(const bf16x8*)(a0p + k0);
        bf16x8 a1 = *(const bf16x8*)(a1p + k0);
        bf16x8 b0 = *(const bf16x8*)(b0p + k0);
        bf16x8 b1 = *(const bf16x8*)(b1p + k0);
        acc[0][0] = __builtin_amdgcn_mfma_f32_16x16x32_bf16(a0, b0, acc[0][0], 0, 0, 0);
        acc[0][1] = __builtin_amdgcn_mfma_f32_16x16x32_bf16(a0, b1, acc[0][1], 0, 0, 0);
        acc[1][0] = __builtin_amdgcn_mfma_f32_16x16x32_bf16(a1, b0, acc[1][0], 0, 0, 0);
        acc[1][1] = __builtin_amdgcn_mfma_f32_16x16x32_bf16(a1, b1, acc[1][1], 0, 0, 0);
    }
    // C/D layout (HW-verified): col = lane&15, row = (lane>>4)*4 + reg
    int crow0 = blockIdx.x * 32 + (l >> 4) * 4;
    int ccol = blockIdx.y * 32 + (l & 15);
    float bias0 = bias[ccol], bias1 = bias[ccol + 16];
#pragma unroll
    for (int m = 0; m < 2; ++m)
#pragma unroll
        for (int nf = 0; nf < 2; ++nf)
#pragma unroll
            for (int q = 0; q < 4; ++q) {
                int r = crow0 + m * 16 + q;
                int c = ccol + nf * 16;
                float v = acc[m][nf][q] + (nf ? bias1 : bias0);
                if (MODE == 0) {
                    ((float*)Cout)[(size_t)r * DD + c] = v;
                } else if (MODE == 1) {
                    v = v / (1.0f + expf(-v));
                    ((bf16_t*)Cout)[(size_t)r * DD + c] = (bf16_t)v;
                } else {
                    ((float*)Cout)[(size_t)r * DD + c] += v;
                }
            }
}

// ---------------- pooling ----------------
__global__ void score_kernel(const float* __restrict__ h, const float* __restrict__ p,
                             float* __restrict__ scores, int n) {
    int r = blockIdx.x;
    int b = r / n, i = r - b * n;
    int d = threadIdx.x;
    float hv = h[r * DD + d], pv = p[d];
    float hp = blockReduceSum256(hv * pv);
    float pp = blockReduceSum256(pv * pv);
    if (d == 0) scores[b * NTOT + i] = hp / sqrtf(pp);
}

// radix-select threshold (k-th largest) + tie-aware stable compaction
__global__ void topk_kernel(const float* __restrict__ scores, const int* __restrict__ orig_cur,
                            int* __restrict__ orig_next, int* __restrict__ idx_local,
                            float* __restrict__ gate, int n, int k) {
    __shared__ unsigned keys[2048];
    __shared__ int hist[256];
    __shared__ int sg[256], se[256];
    __shared__ int sh_bucket, sh_r;
    int b = blockIdx.x;
    const float* sc = scores + b * NTOT;
    int tid = threadIdx.x;
    // order-preserving key: ascending key == ascending float
    for (int i = tid; i < n; i += 256) {
        unsigned u = __float_as_uint(sc[i]);
        keys[i] = (u & 0x80000000u) ? ~u : (u | 0x80000000u);
    }
    if (tid == 0) sh_r = n - k;  // 0-indexed rank in ascending order
    __syncthreads();
    unsigned prefix = 0;
    for (int shift = 24; shift >= 0; shift -= 8) {
        hist[tid] = 0;
        __syncthreads();
        unsigned mask = (shift == 24) ? 0u : (0xFFFFFFFFu << (shift + 8));
        for (int i = tid; i < n; i += 256) {
            unsigned key = keys[i];
            if ((key & mask) == (prefix & mask))
                atomicAdd(&hist[(key >> shift) & 255], 1);
        }
        __syncthreads();
        int cnt = hist[tid];
        sg[tid] = cnt;
        __syncthreads();
        for (int off = 1; off < 256; off <<= 1) {
            int v = (tid >= off) ? sg[tid - off] : 0;
            __syncthreads();
            sg[tid] += v;
            __syncthreads();
        }
        int incl = sg[tid], excl = incl - cnt;
        int r = sh_r;
        if (excl <= r && r < incl) { sh_bucket = tid; sh_r = r - excl; }
        __syncthreads();
        prefix |= ((unsigned)sh_bucket) << shift;
        __syncthreads();
    }
    unsigned uthr = (prefix & 0x80000000u) ? (prefix ^ 0x80000000u) : ~prefix;
    float thr = __uint_as_float(uthr);  // exact k-th largest value
    // per-chunk counts of (>thr) and (==thr)
    int chunk = n / 256;
    int base = tid * chunk;
    int cgt = 0, ceq = 0;
    for (int u = 0; u < chunk; ++u) {
        float s = sc[base + u];
        cgt += (s > thr); ceq += (s == thr);
    }
    sg[tid] = cgt; se[tid] = ceq; __syncthreads();
    for (int off = 1; off < 256; off <<= 1) {
        int vg = (tid >= off) ? sg[tid - off] : 0;
        int ve = (tid >= off) ? se[tid - off] : 0;
        __syncthreads();
        sg[tid] += vg; se[tid] += ve;
        __syncthreads();
    }
    int total_gt = sg[255];
    int ties = k - total_gt;             // how many ==thr to take (lowest indices first)
    int gtb = sg[tid] - cgt, eqb = se[tid] - ceq;  // exclusive prefixes
    for (int u = 0; u < chunk; ++u) {
        int i = base + u;
        float s = sc[i];
        bool isgt = (s > thr), iseq = (s == thr);
        bool keep = isgt || (iseq && eqb < ties);
        if (keep) {
            int pos = gtb + (eqb < ties ? eqb : ties);  // kept-before-i
            idx_local[b * NTOT + pos] = i;
            gate[b * NTOT + pos] = tanhf(s);
            orig_next[b * NTOT + pos] = orig_cur[b * NTOT + i];
        }
        gtb += isgt; eqb += iseq;
    }
}

__global__ void gather_kernel(const float* __restrict__ h, const int* __restrict__ idx_local,
                              const float* __restrict__ gate, float* __restrict__ hout,
                              int n_old, int k) {
    int r = blockIdx.x;  // B*k
    int b = r / k, rr = r - b * k;
    int d = threadIdx.x;
    int src = idx_local[b * NTOT + rr];
    hout[(size_t)r * DD + d] = h[(size_t)(b * n_old + src) * DD + d] * gate[b * NTOT + rr];
}

// ---------------- readout ----------------
__global__ void readout_kernel(const float* __restrict__ h, float* __restrict__ feat) {
    int bd = blockIdx.x;  // B*256
    int b = bd >> 8, d = bd & 255;
    int i = threadIdx.x;  // node (n=256)
    float x = h[(size_t)(b * 256 + i) * DD + d];
    float m = blockReduceSum256(x) / 256.0f;
    float diff = x - m;
    float s2 = blockReduceSum256(diff * diff);
    if (i == 0) {
        feat[b * 512 + d] = m;
        feat[b * 512 + 256 + d] = sqrtf(s2 / 255.0f) + 1e-6f;  // ddof=1
    }
}

__global__ void final_kernel(const float* __restrict__ feat, const float* __restrict__ lw,
                             const float* __restrict__ lb, float* __restrict__ out) {
    int b = blockIdx.x, l = threadIdx.x;  // 128 threads
    float acc = lb[l];
    const float* f = feat + b * 512;
    for (int k = 0; k < 512; ++k) acc += f[k] * lw[k * 128 + l];
    out[b * 128 + l] = acc;
}

extern "C" void kernel_launch(void* const* d_in, const int* in_sizes, int n_in,
                              void* d_out, int out_size, void* d_ws, size_t ws_size,
                              hipStream_t stream) {
    (void)in_sizes; (void)n_in; (void)out_size; (void)ws_size;
    const float* x     = (const float*)d_in[0];
    const float* adj   = (const float*)d_in[1];
    const float* pos   = (const float*)d_in[2];
    const float* in_w  = (const float*)d_in[3];
    const float* in_b  = (const float*)d_in[4];
    const float* pw1   = (const float*)d_in[5];
    const float* pb1   = (const float*)d_in[6];
    const float* pw2   = (const float*)d_in[7];
    const float* pb2   = (const float*)d_in[8];
    const float* bg    = (const float*)d_in[9];
    const float* bb    = (const float*)d_in[10];
    const float* bw1   = (const float*)d_in[11];
    const float* bb1   = (const float*)d_in[12];
    const float* bw2   = (const float*)d_in[13];
    const float* bb2   = (const float*)d_in[14];
    const float* beps  = (const float*)d_in[15];
    const float* poolp = (const float*)d_in[16];
    const float* lw    = (const float*)d_in[17];
    const float* lb    = (const float*)d_in[18];
    float* out = (float*)d_out;

    char* wp = (char*)d_ws;
    auto alloc = [&](size_t bytes) -> void* {
        void* p = (void*)wp;
        wp += (bytes + 255) & ~(size_t)255;
        return p;
    };
    const size_t HBYTES = (size_t)BSZ * NTOT * DD * sizeof(float);  // 8.39 MB
    float*  h    = (float*)alloc(HBYTES);
    float*  bufB = (float*)alloc(HBYTES);          // hn (f32)
    float*  bufC = (float*)alloc(HBYTES);          // pe out / gather target (f32)
    bf16_t* tb   = (bf16_t*)alloc(HBYTES / 2);     // agg out / pe q (bf16)
    bf16_t* ub   = (bf16_t*)alloc(HBYTES / 2);     // mm1 out (bf16)
    bf16_t* Wt   = (bf16_t*)alloc((size_t)17 * DD * DD * sizeof(bf16_t));
    float* stats   = (float*)alloc(8 * sizeof(float));
    float* scores  = (float*)alloc(BSZ * NTOT * sizeof(float));
    float* gate    = (float*)alloc(BSZ * NTOT * sizeof(float));
    int*   origA   = (int*)alloc(BSZ * NTOT * sizeof(int));
    int*   origB   = (int*)alloc(BSZ * NTOT * sizeof(int));
    int*   idxl    = (int*)alloc(BSZ * NTOT * sizeof(int));
    int*   inv     = (int*)alloc(BSZ * NTOT * sizeof(int));
    int*   counts  = (int*)alloc(NTOT * sizeof(int));
    int*   row_ptr = (int*)alloc((NTOT + 1) * sizeof(int));
    int*   col     = (int*)alloc((size_t)NTOT * 64 * sizeof(int));  // cap 64 nbrs/row (mean ~8)
    float* feat    = (float*)alloc(BSZ * 512 * sizeof(float));

    // ---- weight prep (bf16 transposed) ----
    wprep_kernel<<<dim3(17, 16, 16), 256, 0, stream>>>(bw1, bw2, pw2, Wt);
    // ---- positional embedding ----
    pos_stats_kernel<<<1, 256, 0, stream>>>(pos, stats);
    pe_q_kernel<<<NTOT, 256, 0, stream>>>(pos, stats, pw1, pb1, tb);
    mm_bf16<0><<<dim3(NTOT / 32, 8), 64, 0, stream>>>(tb, Wt + (size_t)16 * DD * DD, pb2, bufC, NTOT);
    // ---- h init ----
    init_h_kernel<<<BSZ * NTOT, 256, 0, stream>>>(x, in_w, in_b, bufC, h);
    // ---- CSR of original adjacency ----
    csr_count_kernel<<<NTOT, 256, 0, stream>>>(adj, counts);
    scan_kernel<<<1, 256, 0, stream>>>(counts, row_ptr);
    csr_fill_kernel<<<NTOT, 64, 0, stream>>>(adj, row_ptr, col);
    // ---- index maps ----
    init_maps_kernel<<<(BSZ * NTOT) / 256, 256, 0, stream>>>(origA, inv);

    float* hcur = h;
    int* orig = origA;
    int* orign = origB;
    int n = NTOT;
    int blk = 0;
    for (int dep = 0; dep < 4; ++dep) {
        for (int s = 0; s < 2; ++s) {
            int rows = BSZ * n;
            ln_kernel<<<rows, 256, 0, stream>>>(hcur, bufB, bg + blk * DD, bb + blk * DD);
            agg_kernel<<<rows, 256, 0, stream>>>(bufB, tb, row_ptr, col, orig, inv, beps, blk, n);
            mm_bf16<1><<<dim3(rows / 32, 8), 64, 0, stream>>>(
                tb, Wt + (size_t)blk * DD * DD, bb1 + blk * DD, ub, rows);
            mm_bf16<2><<<dim3(rows / 32, 8), 64, 0, stream>>>(
                ub, Wt + (size_t)(8 + blk) * DD * DD, bb2 + blk * DD, hcur, rows);
            ++blk;
        }
        if (dep < 3) {
            int k = n / 2;
            score_kernel<<<BSZ * n, 256, 0, stream>>>(hcur, poolp + dep * DD, scores, n);
            topk_kernel<<<BSZ, 256, 0, stream>>>(scores, orig, orign, idxl, gate, n, k);
            gather_kernel<<<BSZ * k, 256, 0, stream>>>(hcur, idxl, gate, bufC, n, k);
            { float* t = hcur; hcur = bufC; bufC = t; }
            { int* t = orig; orig = orign; orign = t; }
            inv_reset_kernel<<<(BSZ * NTOT) / 256, 256, 0, stream>>>(inv);
            inv_set_kernel<<<(BSZ * k) / 256, 256, 0, stream>>>(orig, inv, k);
            n = k;
        }
    }
    // ---- readout ----
    readout_kernel<<<BSZ * 256, 256, 0, stream>>>(hcur, feat);
    final_kernel<<<BSZ, 128, 0, stream>>>(feat, lw, lb, out);
}